// Round 1
// baseline (12335.889 us; speedup 1.0000x reference)
//
#include <hip/hip_runtime.h>
#include <hip/hip_bf16.h>

// ---------------------------------------------------------------------------
// SemGCN forward. Structure:
//   att precompute (15 [16,16] masked softmaxes) -> ws
//   per branch: gconv_in (Fin=2) -> 8x gconv_hidden (128x128) -> gconv_out (Fout=3)
//   cat branch: pack merged (Fin=12) -> same stack -> out_final
// Each gconv kernel fuses: BN(stats of producer)+ReLU+residual on load,
// y0=x@W0, y1=x@W1, joint-mix via att, bias, stats accumulation for own BN.
// ---------------------------------------------------------------------------

#define BATCH 8192
#define NJ 16
#define FHID 128
#define NROWS (BATCH * NJ)               // 131072
static const size_t NBJF = (size_t)BATCH * NJ * FHID;  // 16777216 floats

// H36M 16-joint adjacency + diag, row bitmasks (bit j set if mask[i][j])
__constant__ unsigned short kMaskBits[16] = {
    0x0093, 0x0007, 0x000E, 0x000C, 0x0031, 0x0070, 0x0060, 0x0181,
    0x4B80, 0x0700, 0x0600, 0x1900, 0x3800, 0x3000, 0xC100, 0xC000};

// 15 att slots: 0=in, 1=cat, 2..9=res[0..7], 10..14=out[0..4]
__global__ void att_kernel(const float* __restrict__ e_in,
                           const float* __restrict__ e_cat,
                           const float* __restrict__ e_res,
                           const float* __restrict__ e_out,
                           float* __restrict__ att_off,
                           float* __restrict__ attd) {
  int t = threadIdx.x;
  if (t >= 240) return;
  int m = t >> 4, i = t & 15;
  const float* e;
  if (m == 0) e = e_in;
  else if (m == 1) e = e_cat;
  else if (m < 10) e = e_res + (m - 2) * 256;
  else e = e_out + (m - 10) * 256;
  unsigned msk = kMaskBits[i];
  float mx = -3.0e38f;
  for (int j = 0; j < 16; ++j)
    if ((msk >> j) & 1) mx = fmaxf(mx, e[i * 16 + j]);
  float v[16];
  float s = 0.0f;
  for (int j = 0; j < 16; ++j) {
    float val = ((msk >> j) & 1) ? expf(e[i * 16 + j] - mx) : 0.0f;
    v[j] = val;
    s += val;
  }
  float inv = 1.0f / s;
  for (int j = 0; j < 16; ++j)
    att_off[m * 256 + i * 16 + j] = (j == i) ? 0.0f : v[j] * inv;
  attd[m * 16 + i] = v[i] * inv;
}

__device__ __forceinline__ float4 bn_relu4(float4 h, const float* __restrict__ stats,
                                           const float* __restrict__ g,
                                           const float* __restrict__ bt, int c) {
  const float invN = 1.0f / (float)NROWS;
  float4 s1 = *(const float4*)(stats + c);
  float4 s2 = *(const float4*)(stats + FHID + c);
  float4 gg = *(const float4*)(g + c);
  float4 bb = *(const float4*)(bt + c);
  float4 r;
#define BN_DO(X)                                             \
  {                                                          \
    float mu = s1.X * invN;                                  \
    float var = fmaxf(s2.X * invN - mu * mu, 0.0f);          \
    float sc = gg.X / sqrtf(var + 1e-5f);                    \
    float sh = bb.X - mu * sc;                               \
    r.X = fmaxf(0.0f, fmaf(h.X, sc, sh));                    \
  }
  BN_DO(x) BN_DO(y) BN_DO(z) BN_DO(w)
#undef BN_DO
  return r;
}

// One gconv layer. Block: 256 threads = 128 channels x 2 batch elems. Grid: B/2.
// res_mode: bit0 = add residual from resbuf, bit1 = save transformed xin to resbuf.
template <int FIN>
__launch_bounds__(256)
__global__ void gconv_kernel(const float* __restrict__ hin,       // [B,16,FIN] pre-BN (or raw input)
                             const float* __restrict__ stats_in,  // [2][128] or null (no BN)
                             const float* __restrict__ gamma,
                             const float* __restrict__ beta,
                             float* __restrict__ resbuf,          // [B,16,128] or null
                             int res_mode,
                             const float* __restrict__ W,     // [2][FIN][128]
                             const float* __restrict__ bias,  // [128]
                             const float* __restrict__ attoff, // [16][16] diag-zeroed
                             const float* __restrict__ attd_p, // [16]
                             float* __restrict__ hout,         // [B,16,128]
                             float* __restrict__ stats_out) {  // [2][128]
  __shared__ float xin[2][NJ][FIN];
  __shared__ float att_s[256];
  __shared__ float attd_s[16];
  __shared__ float red[256];

  int tid = threadIdx.x;
  int b0 = blockIdx.x * 2;

  att_s[tid] = attoff[tid];
  if (tid < 16) attd_s[tid] = attd_p[tid];

  // ---- phase 1: stage input tile, fused BN+ReLU+residual ----
  const int TOT4 = 2 * NJ * FIN / 4;
  const float4* hin4 = (const float4*)(hin + (size_t)b0 * NJ * FIN);
  float4* res4 = resbuf ? (float4*)(resbuf + (size_t)b0 * NJ * FIN) : nullptr;
  for (int k = tid; k < TOT4; k += 256) {
    float4 h = hin4[k];
    if (stats_in) {  // only used when FIN==128
      int c = (k * 4) % FIN;
      h = bn_relu4(h, stats_in, gamma, beta, c);
    }
    if (res_mode & 1) {
      float4 r = res4[k];
      h.x += r.x; h.y += r.y; h.z += r.z; h.w += r.w;
    }
    if (res_mode & 2) res4[k] = h;
    ((float4*)&xin[0][0][0])[k] = h;
  }
  __syncthreads();

  // ---- phase 2: y0 = x@W0, y1 = x@W1 for all 16 joints of my (b, o) ----
  int o = tid & 127;
  int bl = tid >> 7;
  float acc0[16], acc1[16];
#pragma unroll
  for (int j = 0; j < 16; ++j) { acc0[j] = 0.0f; acc1[j] = 0.0f; }
  const float* W0 = W;
  const float* W1 = W + FIN * FHID;
  if constexpr (FIN % 4 == 0) {
    for (int f = 0; f < FIN; f += 4) {
      float w00 = W0[(f + 0) * FHID + o], w01 = W0[(f + 1) * FHID + o];
      float w02 = W0[(f + 2) * FHID + o], w03 = W0[(f + 3) * FHID + o];
      float w10 = W1[(f + 0) * FHID + o], w11 = W1[(f + 1) * FHID + o];
      float w12 = W1[(f + 2) * FHID + o], w13 = W1[(f + 3) * FHID + o];
#pragma unroll
      for (int j = 0; j < 16; ++j) {
        float4 xv = *(const float4*)&xin[bl][j][f];
        acc0[j] = fmaf(xv.x, w00, fmaf(xv.y, w01, fmaf(xv.z, w02, fmaf(xv.w, w03, acc0[j]))));
        acc1[j] = fmaf(xv.x, w10, fmaf(xv.y, w11, fmaf(xv.z, w12, fmaf(xv.w, w13, acc1[j]))));
      }
    }
  } else {
    for (int f = 0; f < FIN; ++f) {
      float w0 = W0[f * FHID + o], w1 = W1[f * FHID + o];
#pragma unroll
      for (int j = 0; j < 16; ++j) {
        float xv = xin[bl][j][f];
        acc0[j] = fmaf(xv, w0, acc0[j]);
        acc1[j] = fmaf(xv, w1, acc1[j]);
      }
    }
  }

  // ---- phase 3: joint mix + bias, write out, accumulate BN stats ----
  float bo = bias[o];
  float ssum = 0.0f, ssq = 0.0f;
  size_t b = (size_t)b0 + bl;
#pragma unroll
  for (int i = 0; i < 16; ++i) {
    float h = fmaf(attd_s[i], acc0[i], bo);
#pragma unroll
    for (int j = 0; j < 16; ++j) h = fmaf(att_s[i * 16 + j], acc1[j], h);
    hout[(b * NJ + i) * FHID + o] = h;
    ssum += h;
    ssq = fmaf(h, h, ssq);
  }
  if (stats_out) {
    __syncthreads();
    red[tid] = ssum;
    __syncthreads();
    if (bl == 0) atomicAdd(&stats_out[o], ssum + red[o + 128]);
    __syncthreads();
    red[tid] = ssq;
    __syncthreads();
    if (bl == 0) atomicAdd(&stats_out[FHID + o], ssq + red[o + 128]);
  }
}

// Output gconv (Fin=128, Fout=3). Block: 256 = 16 batch x 16 joints. Grid: B/16.
// Always applies BN (stats_in) + residual add.
__launch_bounds__(256)
__global__ void gconv_out_kernel(const float* __restrict__ hin,
                                 const float* __restrict__ stats_in,
                                 const float* __restrict__ gamma,
                                 const float* __restrict__ beta,
                                 const float* __restrict__ resbuf,
                                 const float* __restrict__ W,     // [2][128][3]
                                 const float* __restrict__ bias,  // [3]
                                 const float* __restrict__ attoff,
                                 const float* __restrict__ attd_p,
                                 float* __restrict__ out) {       // [B,16,3]
  __shared__ float y0[16][16][3];
  __shared__ float y1[16][16][3];
  __shared__ float att_s[256];
  __shared__ float attd_s[16];
  int tid = threadIdx.x;
  att_s[tid] = attoff[tid];
  if (tid < 16) attd_s[tid] = attd_p[tid];
  int bl = tid >> 4, i = tid & 15;
  size_t row = ((size_t)blockIdx.x * 16 + bl) * NJ + i;
  const float* hrow = hin + row * FHID;
  const float* rrow = resbuf + row * FHID;
  const float* W0 = W;
  const float* W1 = W + 384;
  float a0[3] = {0, 0, 0}, a1[3] = {0, 0, 0};
  for (int f = 0; f < FHID; f += 4) {
    float4 h = *(const float4*)(hrow + f);
    h = bn_relu4(h, stats_in, gamma, beta, f);
    float4 r = *(const float4*)(rrow + f);
    h.x += r.x; h.y += r.y; h.z += r.z; h.w += r.w;
    float xs[4] = {h.x, h.y, h.z, h.w};
#pragma unroll
    for (int c = 0; c < 4; ++c) {
#pragma unroll
      for (int o = 0; o < 3; ++o) {
        a0[o] = fmaf(xs[c], W0[(f + c) * 3 + o], a0[o]);
        a1[o] = fmaf(xs[c], W1[(f + c) * 3 + o], a1[o]);
      }
    }
  }
#pragma unroll
  for (int o = 0; o < 3; ++o) {
    y0[bl][i][o] = a0[o];
    y1[bl][i][o] = a1[o];
  }
  __syncthreads();
#pragma unroll
  for (int o = 0; o < 3; ++o) {
    float v = fmaf(attd_s[i], y0[bl][i][o], bias[o]);
#pragma unroll
    for (int j = 0; j < 16; ++j) v = fmaf(att_s[i * 16 + j], y1[bl][j][o], v);
    out[row * 3 + o] = v;
  }
}

// merged[b,j,c] = out_{1+c/3}[b,j,c%3]; out_i lives at d_out + i*393216
__global__ void pack_merged(const float* __restrict__ dout, float* __restrict__ merged) {
  int idx = blockIdx.x * 256 + threadIdx.x;
  if (idx >= BATCH * NJ * 12) return;
  int c = idx % 12;
  int bj = idx / 12;
  merged[idx] = dout[(size_t)(1 + c / 3) * 393216 + (size_t)bj * 3 + (c % 3)];
}

extern "C" void kernel_launch(void* const* d_in, const int* in_sizes, int n_in,
                              void* d_out, int out_size, void* d_ws, size_t ws_size,
                              hipStream_t stream) {
  (void)in_sizes; (void)n_in; (void)out_size; (void)ws_size;
  const float* W_in = (const float*)d_in[4];
  const float* b_in = (const float*)d_in[5];
  const float* e_in = (const float*)d_in[6];
  const float* g_in = (const float*)d_in[7];
  const float* beta_in = (const float*)d_in[8];
  const float* W_cat = (const float*)d_in[9];
  const float* b_cat = (const float*)d_in[10];
  const float* e_cat = (const float*)d_in[11];
  const float* g_cat = (const float*)d_in[12];
  const float* beta_cat = (const float*)d_in[13];
  const float* W_res = (const float*)d_in[14];
  const float* b_res = (const float*)d_in[15];
  const float* e_res = (const float*)d_in[16];
  const float* g_res = (const float*)d_in[17];
  const float* beta_res = (const float*)d_in[18];
  const float* W_out = (const float*)d_in[19];
  const float* b_out = (const float*)d_in[20];
  const float* e_out = (const float*)d_in[21];

  float* ws = (float*)d_ws;
  float* att_off = ws;                      // 15*256
  float* attd = att_off + 15 * 256;         // 15*16
  float* stats = attd + 15 * 16;            // 45 slots x 256
  float* merged = stats + 45 * 256;         // B*16*12
  float* hA = merged + (size_t)BATCH * NJ * 12;
  float* hB = hA + NBJF;
  float* R = hB + NBJF;

  hipMemsetAsync(stats, 0, 45 * 256 * sizeof(float), stream);
  att_kernel<<<1, 256, 0, stream>>>(e_in, e_cat, e_res, e_out, att_off, attd);

  float* dout = (float*)d_out;

  // shared res-stack + out-layer runner. sb = stats slot base for this stack.
  auto run_stack = [&](int sb, const float* g0, const float* bt0, const float* Wo,
                       const float* bo, int att_out_slot, float* optr) {
    for (int k = 0; k < 8; ++k) {
      const float* hi = (k % 2 == 0) ? hA : hB;
      float* ho = (k % 2 == 0) ? hB : hA;
      const float* gg = (k == 0) ? g0 : g_res + (size_t)(k - 1) * FHID;
      const float* bb = (k == 0) ? bt0 : beta_res + (size_t)(k - 1) * FHID;
      // k==0: save xin (residual r1); k even>=2: add old residual + save new; odd: none
      int rm = (k == 0) ? 2 : ((k % 2 == 0) ? 3 : 0);
      gconv_kernel<128><<<BATCH / 2, 256, 0, stream>>>(
          hi, stats + (size_t)(sb + k) * 256, gg, bb, rm ? R : nullptr, rm,
          W_res + (size_t)k * 2 * FHID * FHID, b_res + (size_t)k * FHID,
          att_off + (size_t)(2 + k) * 256, attd + (size_t)(2 + k) * 16, ho,
          stats + (size_t)(sb + k + 1) * 256);
    }
    gconv_out_kernel<<<BATCH / 16, 256, 0, stream>>>(
        hA, stats + (size_t)(sb + 8) * 256, g_res + 7 * FHID, beta_res + 7 * FHID,
        R, Wo, bo, att_off + (size_t)att_out_slot * 256,
        attd + (size_t)att_out_slot * 16, optr);
  };

  for (int bi = 0; bi < 4; ++bi) {
    gconv_kernel<2><<<BATCH / 2, 256, 0, stream>>>(
        (const float*)d_in[bi], nullptr, nullptr, nullptr, nullptr, 0, W_in, b_in,
        att_off, attd, hA, stats + (size_t)(bi * 9) * 256);
    run_stack(bi * 9, g_in, beta_in, W_out + (size_t)bi * 768, b_out + bi * 3,
              10 + bi, dout + (size_t)(1 + bi) * 393216);
  }

  pack_merged<<<(BATCH * NJ * 12 + 255) / 256, 256, 0, stream>>>(dout, merged);
  gconv_kernel<12><<<BATCH / 2, 256, 0, stream>>>(
      merged, nullptr, nullptr, nullptr, nullptr, 0, W_cat, b_cat, att_off + 256,
      attd + 16, hA, stats + (size_t)36 * 256);
  run_stack(36, g_cat, beta_cat, W_out + (size_t)4 * 768, b_out + 12, 14, dout);
}

// Round 2
// 4631.919 us; speedup vs baseline: 2.6632x; 2.6632x over previous
//
#include <hip/hip_runtime.h>
#include <hip/hip_bf16.h>

// ---------------------------------------------------------------------------
// SemGCN forward.
//   att precompute (15 [16,16] masked softmaxes) -> ws
//   W_res pre-packed to bf16 MFMA B-fragment layout -> ws  (once per launch)
//   heavy 128x128 layers: MFMA kernel, block = 8 batch elems (128 rows):
//     stage: fp32 load + BN+ReLU+residual -> bf16 A-frags in LDS
//     GEMM [128x128]x[128x256] via mfma_f32_16x16x32_bf16 (fp32 accum)
//     epilogue: joint-mix via LDS round-trip + bias + BN-stats atomics
//   in/cat/out layers (tiny K or N): original fp32 VALU kernels
// ---------------------------------------------------------------------------

#define BATCH 8192
#define NJ 16
#define FHID 128
#define NROWS (BATCH * NJ)               // 131072
static const size_t NBJF = (size_t)BATCH * NJ * FHID;  // 16777216 floats

using frag_ab = __attribute__((ext_vector_type(8))) short;   // 8 bf16
using frag_cd = __attribute__((ext_vector_type(4))) float;   // 4 fp32

__device__ __forceinline__ unsigned short f2bf(float f) {
  unsigned u = __float_as_uint(f);
  u = u + 0x7FFF + ((u >> 16) & 1);   // RNE
  return (unsigned short)(u >> 16);
}

// H36M 16-joint adjacency + diag, row bitmasks (bit j set if mask[i][j])
__constant__ unsigned short kMaskBits[16] = {
    0x0093, 0x0007, 0x000E, 0x000C, 0x0031, 0x0070, 0x0060, 0x0181,
    0x4B80, 0x0700, 0x0600, 0x1900, 0x3800, 0x3000, 0xC100, 0xC000};

// 15 att slots: 0=in, 1=cat, 2..9=res[0..7], 10..14=out[0..4]
__global__ void att_kernel(const float* __restrict__ e_in,
                           const float* __restrict__ e_cat,
                           const float* __restrict__ e_res,
                           const float* __restrict__ e_out,
                           float* __restrict__ att_off,
                           float* __restrict__ attd) {
  int t = threadIdx.x;
  if (t >= 240) return;
  int m = t >> 4, i = t & 15;
  const float* e;
  if (m == 0) e = e_in;
  else if (m == 1) e = e_cat;
  else if (m < 10) e = e_res + (m - 2) * 256;
  else e = e_out + (m - 10) * 256;
  unsigned msk = kMaskBits[i];
  float mx = -3.0e38f;
  for (int j = 0; j < 16; ++j)
    if ((msk >> j) & 1) mx = fmaxf(mx, e[i * 16 + j]);
  float v[16];
  float s = 0.0f;
  for (int j = 0; j < 16; ++j) {
    float val = ((msk >> j) & 1) ? expf(e[i * 16 + j] - mx) : 0.0f;
    v[j] = val;
    s += val;
  }
  float inv = 1.0f / s;
  for (int j = 0; j < 16; ++j)
    att_off[m * 256 + i * 16 + j] = (j == i) ? 0.0f : v[j] * inv;
  attd[m * 16 + i] = v[i] * inv;
}

// Pack W_res[8][2][128][128] fp32 -> bf16 B-fragments.
// Frag (kk,nt): lane l holds B[k=kk*32+(l>>4)*8+j][n=nt*16+(l&15)], j=0..7.
// n<128 -> W0 col n ; n>=128 -> W1 col n-128.  Frag stride 512 bf16 (no pad).
__global__ void pack_w_kernel(const float* __restrict__ W_res,
                              short* __restrict__ Wpk) {
  int idx = blockIdx.x * 256 + threadIdx.x;   // 8*64*64 = 32768 total
  int lane = idx & 63;
  int frag = (idx >> 6) & 63;                 // kk*16+nt
  int layer = idx >> 12;
  int kk = frag >> 4, nt = frag & 15;
  int n = nt * 16 + (lane & 15);
  int kbase = kk * 32 + (lane >> 4) * 8;
  int mat = n >> 7, c = n & 127;
  const float* Wsrc = W_res + (((size_t)layer * 2 + mat) * 128) * 128;
  short* dst = Wpk + ((size_t)(layer * 64 + frag)) * 512 + lane * 8;
#pragma unroll
  for (int j = 0; j < 8; ++j)
    dst[j] = (short)f2bf(Wsrc[(size_t)(kbase + j) * 128 + c]);
}

__device__ __forceinline__ float4 bn_relu4(float4 h, const float* __restrict__ stats,
                                           const float* __restrict__ g,
                                           const float* __restrict__ bt, int c) {
  const float invN = 1.0f / (float)NROWS;
  float4 s1 = *(const float4*)(stats + c);
  float4 s2 = *(const float4*)(stats + FHID + c);
  float4 gg = *(const float4*)(g + c);
  float4 bb = *(const float4*)(bt + c);
  float4 r;
#define BN_DO(X)                                             \
  {                                                          \
    float mu = s1.X * invN;                                  \
    float var = fmaxf(s2.X * invN - mu * mu, 0.0f);          \
    float sc = gg.X / sqrtf(var + 1e-5f);                    \
    float sh = bb.X - mu * sc;                               \
    r.X = fmaxf(0.0f, fmaf(h.X, sc, sh));                    \
  }
  BN_DO(x) BN_DO(y) BN_DO(z) BN_DO(w)
#undef BN_DO
  return r;
}

// ---------------------------------------------------------------------------
// Heavy layer (Fin=Fout=128) via MFMA. Block 256 = 4 waves, 8 batch elems.
// Grid BATCH/8 = 1024. res_mode: bit0 = add residual, bit1 = save residual.
// ---------------------------------------------------------------------------
#define FRAG_STRIDE 520   // bf16 units per A-frag in LDS (pad 8 to spread banks)

__launch_bounds__(256, 3)
__global__ void gconv_mfma_kernel(const float* __restrict__ hin,       // [B,16,128] pre-BN
                                  const float* __restrict__ stats_in,  // [2][128]
                                  const float* __restrict__ gamma,
                                  const float* __restrict__ beta,
                                  float* __restrict__ resbuf,
                                  int res_mode,
                                  const short* __restrict__ Wpk,   // packed [4][16][64][8] bf16
                                  const float* __restrict__ bias,  // [128]
                                  const float* __restrict__ attoff,
                                  const float* __restrict__ attd_p,
                                  float* __restrict__ hout,        // [B,16,128]
                                  float* __restrict__ stats_out) { // [2][128]
  __shared__ short Apk[32 * FRAG_STRIDE];          // 8 mt x 4 kk frags
  __shared__ float mixb[4][2][16 * 33];            // [wave][y0/y1][j][colIdx]
  __shared__ float att_s[256];
  __shared__ float attd_s[16];

  int tid = threadIdx.x;
  int b0 = blockIdx.x * 8;

  att_s[tid] = attoff[tid];
  if (tid < 16) attd_s[tid] = attd_p[tid];

  // ---- stage: 128 rows x 128 ch, fused BN+ReLU+residual, pack A-frags ----
  const float* hbase = hin + (size_t)b0 * NJ * FHID;
  float* rbase = resbuf ? resbuf + (size_t)b0 * NJ * FHID : nullptr;
#pragma unroll
  for (int iter = 0; iter < 8; ++iter) {
    int g = iter * 256 + tid;          // 0..2047
    int r = g >> 4;                    // row 0..127
    int c8 = g & 15;                   // 8-channel chunk
    int ch = c8 * 8;
    const float* src = hbase + (size_t)r * FHID + ch;
    float4 h0 = *(const float4*)src;
    float4 h1 = *(const float4*)(src + 4);
    h0 = bn_relu4(h0, stats_in, gamma, beta, ch);
    h1 = bn_relu4(h1, stats_in, gamma, beta, ch + 4);
    if (res_mode & 1) {
      float4 r0 = *(const float4*)(rbase + (size_t)r * FHID + ch);
      float4 r1 = *(const float4*)(rbase + (size_t)r * FHID + ch + 4);
      h0.x += r0.x; h0.y += r0.y; h0.z += r0.z; h0.w += r0.w;
      h1.x += r1.x; h1.y += r1.y; h1.z += r1.z; h1.w += r1.w;
    }
    if (res_mode & 2) {
      *(float4*)(rbase + (size_t)r * FHID + ch) = h0;
      *(float4*)(rbase + (size_t)r * FHID + ch + 4) = h1;
    }
    int mt = r >> 4, m = r & 15, kk = c8 >> 2, sub = c8 & 3;
    int lfrag = mt * 4 + kk;
    int l = m + 16 * sub;
    frag_ab v;
    v[0] = (short)f2bf(h0.x); v[1] = (short)f2bf(h0.y);
    v[2] = (short)f2bf(h0.z); v[3] = (short)f2bf(h0.w);
    v[4] = (short)f2bf(h1.x); v[5] = (short)f2bf(h1.y);
    v[6] = (short)f2bf(h1.z); v[7] = (short)f2bf(h1.w);
    *(frag_ab*)&Apk[lfrag * FRAG_STRIDE + l * 8] = v;
  }
  __syncthreads();

  // ---- GEMM + epilogue. Wave wv owns N-tiles {wv, wv+4, wv+8, wv+12} ----
  int wv = tid >> 6, lane = tid & 63;
  int cIdx = lane & 31;
  int iBase = (lane >> 5) * 8;
  int col = (cIdx < 16) ? (wv * 16 + cIdx) : (64 + wv * 16 + (cIdx - 16));
  float bcol = bias[col];
  float ssum = 0.0f, ssq = 0.0f;

  for (int half = 0; half < 2; ++half) {
    frag_cd acc[4][4] = {};   // [mt-in-half][nt-idx]
#pragma unroll
    for (int kk = 0; kk < 4; ++kk) {
      frag_ab bfr[4], afr[4];
#pragma unroll
      for (int t = 0; t < 4; ++t) {
        int nt = wv + 4 * t;
        bfr[t] = *(const frag_ab*)(Wpk + ((size_t)(kk * 16 + nt) * 64 + lane) * 8);
      }
#pragma unroll
      for (int mi = 0; mi < 4; ++mi) {
        int mt = half * 4 + mi;
        afr[mi] = *(const frag_ab*)&Apk[(mt * 4 + kk) * FRAG_STRIDE + lane * 8];
      }
#pragma unroll
      for (int mi = 0; mi < 4; ++mi)
#pragma unroll
        for (int t = 0; t < 4; ++t)
          acc[mi][t] = __builtin_amdgcn_mfma_f32_16x16x32_bf16(afr[mi], bfr[t],
                                                               acc[mi][t], 0, 0, 0);
    }

    // epilogue: per batch elem (M-tile), joint mix in LDS
    int r0 = (lane >> 4) * 4;
    int cw = lane & 15;
    for (int mi = 0; mi < 4; ++mi) {
      __syncthreads();
#pragma unroll
      for (int t = 0; t < 4; ++t) {
        float* buf = mixb[wv][t >> 1];
        int ci = (t & 1) * 16 + cw;
#pragma unroll
        for (int reg = 0; reg < 4; ++reg)
          buf[(r0 + reg) * 33 + ci] = acc[mi][t][reg];
      }
      __syncthreads();
      size_t b = (size_t)b0 + half * 4 + mi;
      float* outrow = hout + b * NJ * FHID;
#pragma unroll
      for (int t = 0; t < 8; ++t) {
        int i = iBase + t;
        float h = fmaf(attd_s[i], mixb[wv][0][i * 33 + cIdx], bcol);
#pragma unroll
        for (int j = 0; j < 16; ++j)
          h = fmaf(att_s[i * 16 + j], mixb[wv][1][j * 33 + cIdx], h);
        outrow[i * FHID + col] = h;
        ssum += h;
        ssq = fmaf(h, h, ssq);
      }
    }
  }

  // ---- BN stats for this layer's output ----
  ssum += __shfl_xor(ssum, 32);
  ssq += __shfl_xor(ssq, 32);
  if (lane < 32) {
    atomicAdd(&stats_out[col], ssum);
    atomicAdd(&stats_out[FHID + col], ssq);
  }
}

// ---------------------------------------------------------------------------
// Small-K layers (Fin=2 input, Fin=12 cat): original fp32 VALU kernel.
// Block: 256 threads = 128 channels x 2 batch elems. Grid: B/2.
// ---------------------------------------------------------------------------
template <int FIN>
__launch_bounds__(256)
__global__ void gconv_kernel(const float* __restrict__ hin,
                             const float* __restrict__ stats_in,
                             const float* __restrict__ gamma,
                             const float* __restrict__ beta,
                             float* __restrict__ resbuf,
                             int res_mode,
                             const float* __restrict__ W,
                             const float* __restrict__ bias,
                             const float* __restrict__ attoff,
                             const float* __restrict__ attd_p,
                             float* __restrict__ hout,
                             float* __restrict__ stats_out) {
  __shared__ float xin[2][NJ][FIN];
  __shared__ float att_s[256];
  __shared__ float attd_s[16];
  __shared__ float red[256];

  int tid = threadIdx.x;
  int b0 = blockIdx.x * 2;

  att_s[tid] = attoff[tid];
  if (tid < 16) attd_s[tid] = attd_p[tid];

  const int TOT4 = 2 * NJ * FIN / 4;
  const float4* hin4 = (const float4*)(hin + (size_t)b0 * NJ * FIN);
  float4* res4 = resbuf ? (float4*)(resbuf + (size_t)b0 * NJ * FIN) : nullptr;
  for (int k = tid; k < TOT4; k += 256) {
    float4 h = hin4[k];
    if (stats_in) {
      int c = (k * 4) % FIN;
      h = bn_relu4(h, stats_in, gamma, beta, c);
    }
    if (res_mode & 1) {
      float4 r = res4[k];
      h.x += r.x; h.y += r.y; h.z += r.z; h.w += r.w;
    }
    if (res_mode & 2) res4[k] = h;
    ((float4*)&xin[0][0][0])[k] = h;
  }
  __syncthreads();

  int o = tid & 127;
  int bl = tid >> 7;
  float acc0[16], acc1[16];
#pragma unroll
  for (int j = 0; j < 16; ++j) { acc0[j] = 0.0f; acc1[j] = 0.0f; }
  const float* W0 = W;
  const float* W1 = W + FIN * FHID;
  if constexpr (FIN % 4 == 0) {
    for (int f = 0; f < FIN; f += 4) {
      float w00 = W0[(f + 0) * FHID + o], w01 = W0[(f + 1) * FHID + o];
      float w02 = W0[(f + 2) * FHID + o], w03 = W0[(f + 3) * FHID + o];
      float w10 = W1[(f + 0) * FHID + o], w11 = W1[(f + 1) * FHID + o];
      float w12 = W1[(f + 2) * FHID + o], w13 = W1[(f + 3) * FHID + o];
#pragma unroll
      for (int j = 0; j < 16; ++j) {
        float4 xv = *(const float4*)&xin[bl][j][f];
        acc0[j] = fmaf(xv.x, w00, fmaf(xv.y, w01, fmaf(xv.z, w02, fmaf(xv.w, w03, acc0[j]))));
        acc1[j] = fmaf(xv.x, w10, fmaf(xv.y, w11, fmaf(xv.z, w12, fmaf(xv.w, w13, acc1[j]))));
      }
    }
  } else {
    for (int f = 0; f < FIN; ++f) {
      float w0 = W0[f * FHID + o], w1 = W1[f * FHID + o];
#pragma unroll
      for (int j = 0; j < 16; ++j) {
        float xv = xin[bl][j][f];
        acc0[j] = fmaf(xv, w0, acc0[j]);
        acc1[j] = fmaf(xv, w1, acc1[j]);
      }
    }
  }

  float bo = bias[o];
  float ssum = 0.0f, ssq = 0.0f;
  size_t b = (size_t)b0 + bl;
#pragma unroll
  for (int i = 0; i < 16; ++i) {
    float h = fmaf(attd_s[i], acc0[i], bo);
#pragma unroll
    for (int j = 0; j < 16; ++j) h = fmaf(att_s[i * 16 + j], acc1[j], h);
    hout[(b * NJ + i) * FHID + o] = h;
    ssum += h;
    ssq = fmaf(h, h, ssq);
  }
  if (stats_out) {
    __syncthreads();
    red[tid] = ssum;
    __syncthreads();
    if (bl == 0) atomicAdd(&stats_out[o], ssum + red[o + 128]);
    __syncthreads();
    red[tid] = ssq;
    __syncthreads();
    if (bl == 0) atomicAdd(&stats_out[FHID + o], ssq + red[o + 128]);
  }
}

// Output gconv (Fin=128, Fout=3). Block: 256 = 16 batch x 16 joints. Grid: B/16.
__launch_bounds__(256)
__global__ void gconv_out_kernel(const float* __restrict__ hin,
                                 const float* __restrict__ stats_in,
                                 const float* __restrict__ gamma,
                                 const float* __restrict__ beta,
                                 const float* __restrict__ resbuf,
                                 const float* __restrict__ W,     // [2][128][3]
                                 const float* __restrict__ bias,  // [3]
                                 const float* __restrict__ attoff,
                                 const float* __restrict__ attd_p,
                                 float* __restrict__ out) {       // [B,16,3]
  __shared__ float y0[16][16][3];
  __shared__ float y1[16][16][3];
  __shared__ float att_s[256];
  __shared__ float attd_s[16];
  int tid = threadIdx.x;
  att_s[tid] = attoff[tid];
  if (tid < 16) attd_s[tid] = attd_p[tid];
  int bl = tid >> 4, i = tid & 15;
  size_t row = ((size_t)blockIdx.x * 16 + bl) * NJ + i;
  const float* hrow = hin + row * FHID;
  const float* rrow = resbuf + row * FHID;
  const float* W0 = W;
  const float* W1 = W + 384;
  float a0[3] = {0, 0, 0}, a1[3] = {0, 0, 0};
  for (int f = 0; f < FHID; f += 4) {
    float4 h = *(const float4*)(hrow + f);
    h = bn_relu4(h, stats_in, gamma, beta, f);
    float4 r = *(const float4*)(rrow + f);
    h.x += r.x; h.y += r.y; h.z += r.z; h.w += r.w;
    float xs[4] = {h.x, h.y, h.z, h.w};
#pragma unroll
    for (int c = 0; c < 4; ++c) {
#pragma unroll
      for (int o = 0; o < 3; ++o) {
        a0[o] = fmaf(xs[c], W0[(f + c) * 3 + o], a0[o]);
        a1[o] = fmaf(xs[c], W1[(f + c) * 3 + o], a1[o]);
      }
    }
  }
#pragma unroll
  for (int o = 0; o < 3; ++o) {
    y0[bl][i][o] = a0[o];
    y1[bl][i][o] = a1[o];
  }
  __syncthreads();
#pragma unroll
  for (int o = 0; o < 3; ++o) {
    float v = fmaf(attd_s[i], y0[bl][i][o], bias[o]);
#pragma unroll
    for (int j = 0; j < 16; ++j) v = fmaf(att_s[i * 16 + j], y1[bl][j][o], v);
    out[row * 3 + o] = v;
  }
}

// merged[b,j,c] = out_{1+c/3}[b,j,c%3]; out_i lives at d_out + i*393216
__global__ void pack_merged(const float* __restrict__ dout, float* __restrict__ merged) {
  int idx = blockIdx.x * 256 + threadIdx.x;
  if (idx >= BATCH * NJ * 12) return;
  int c = idx % 12;
  int bj = idx / 12;
  merged[idx] = dout[(size_t)(1 + c / 3) * 393216 + (size_t)bj * 3 + (c % 3)];
}

extern "C" void kernel_launch(void* const* d_in, const int* in_sizes, int n_in,
                              void* d_out, int out_size, void* d_ws, size_t ws_size,
                              hipStream_t stream) {
  (void)in_sizes; (void)n_in; (void)out_size; (void)ws_size;
  const float* W_in = (const float*)d_in[4];
  const float* b_in = (const float*)d_in[5];
  const float* e_in = (const float*)d_in[6];
  const float* g_in = (const float*)d_in[7];
  const float* beta_in = (const float*)d_in[8];
  const float* W_cat = (const float*)d_in[9];
  const float* b_cat = (const float*)d_in[10];
  const float* e_cat = (const float*)d_in[11];
  const float* g_cat = (const float*)d_in[12];
  const float* beta_cat = (const float*)d_in[13];
  const float* W_res = (const float*)d_in[14];
  const float* b_res = (const float*)d_in[15];
  const float* e_res = (const float*)d_in[16];
  const float* g_res = (const float*)d_in[17];
  const float* beta_res = (const float*)d_in[18];
  const float* W_out = (const float*)d_in[19];
  const float* b_out = (const float*)d_in[20];
  const float* e_out = (const float*)d_in[21];

  float* ws = (float*)d_ws;
  float* att_off = ws;                              // 15*256
  float* attd = att_off + 15 * 256;                 // 15*16
  float* stats = attd + 15 * 16;                    // 45 slots x 256
  short* Wpk = (short*)(stats + 45 * 256);          // 8*64*512 bf16 = 131072 floats
  float* merged = stats + 45 * 256 + 131072;        // B*16*12
  float* hA = merged + (size_t)BATCH * NJ * 12;
  float* hB = hA + NBJF;
  float* R = hB + NBJF;

  hipMemsetAsync(stats, 0, 45 * 256 * sizeof(float), stream);
  att_kernel<<<1, 256, 0, stream>>>(e_in, e_cat, e_res, e_out, att_off, attd);
  pack_w_kernel<<<128, 256, 0, stream>>>(W_res, Wpk);

  float* dout = (float*)d_out;

  auto run_stack = [&](int sb, const float* g0, const float* bt0, const float* Wo,
                       const float* bo, int att_out_slot, float* optr) {
    for (int k = 0; k < 8; ++k) {
      const float* hi = (k % 2 == 0) ? hA : hB;
      float* ho = (k % 2 == 0) ? hB : hA;
      const float* gg = (k == 0) ? g0 : g_res + (size_t)(k - 1) * FHID;
      const float* bb = (k == 0) ? bt0 : beta_res + (size_t)(k - 1) * FHID;
      int rm = (k == 0) ? 2 : ((k % 2 == 0) ? 3 : 0);
      gconv_mfma_kernel<<<BATCH / 8, 256, 0, stream>>>(
          hi, stats + (size_t)(sb + k) * 256, gg, bb, rm ? R : nullptr, rm,
          Wpk + (size_t)k * 64 * 512, b_res + (size_t)k * FHID,
          att_off + (size_t)(2 + k) * 256, attd + (size_t)(2 + k) * 16, ho,
          stats + (size_t)(sb + k + 1) * 256);
    }
    gconv_out_kernel<<<BATCH / 16, 256, 0, stream>>>(
        hA, stats + (size_t)(sb + 8) * 256, g_res + 7 * FHID, beta_res + 7 * FHID,
        R, Wo, bo, att_off + (size_t)att_out_slot * 256,
        attd + (size_t)att_out_slot * 16, optr);
  };

  for (int bi = 0; bi < 4; ++bi) {
    gconv_kernel<2><<<BATCH / 2, 256, 0, stream>>>(
        (const float*)d_in[bi], nullptr, nullptr, nullptr, nullptr, 0, W_in, b_in,
        att_off, attd, hA, stats + (size_t)(bi * 9) * 256);
    run_stack(bi * 9, g_in, beta_in, W_out + (size_t)bi * 768, b_out + bi * 3,
              10 + bi, dout + (size_t)(1 + bi) * 393216);
  }

  pack_merged<<<(BATCH * NJ * 12 + 255) / 256, 256, 0, stream>>>(dout, merged);
  gconv_kernel<12><<<BATCH / 2, 256, 0, stream>>>(
      merged, nullptr, nullptr, nullptr, nullptr, 0, W_cat, b_cat, att_off + 256,
      attd + 16, hA, stats + (size_t)36 * 256);
  run_stack(36, g_cat, beta_cat, W_out + (size_t)4 * 768, b_out + 12, 14, dout);
}

// Round 3
// 1805.121 us; speedup vs baseline: 6.8338x; 2.5660x over previous
//
#include <hip/hip_runtime.h>
#include <hip/hip_bf16.h>

// ---------------------------------------------------------------------------
// SemGCN forward, round 3.
//  * h / R live in bf16 "blocked" layout: addr(b,c,i) = b*2048 + (c>>3)*128
//    + i*8 + (c&7)  [bf16 units]. A 16x16x32 MFMA A-fragment = one coalesced
//    16B/lane global load; the epilogue C-fragment stores = 8B/lane coalesced.
//  * BN stats: [32 slices][256] (sum | sumsq), slice = blockIdx&31; consumer
//    reduces slices to LDS sc/sh once per block. Kills atomic serialization.
//  * joint-mix done by MFMA: stage-1 C-frag reinterpreted as A-frag == Y^T,
//    Out^T = Y0^T*Bd + Y1^T*Boff with att as precomputed bf16 B-fragments.
//  * heavy GEMM output written in place (blocks own disjoint batch ranges).
// ---------------------------------------------------------------------------

#define BATCH 8192
#define NJ 16
#define FHID 128
#define NROWS (BATCH * NJ)   // 131072
#define NSLICE 32

typedef unsigned short u16;
typedef __attribute__((ext_vector_type(8))) short frag_ab;  // 8 bf16
typedef __attribute__((ext_vector_type(4))) short frag16;   // 4 bf16
typedef __attribute__((ext_vector_type(4))) float frag_cd;  // 4 fp32

__device__ __forceinline__ unsigned short f2bf(float f) {
  unsigned u = __float_as_uint(f);
  u = u + 0x7FFF + ((u >> 16) & 1);  // RNE
  return (unsigned short)(u >> 16);
}
__device__ __forceinline__ float bf2f(unsigned short s) {
  return __uint_as_float((unsigned)s << 16);
}

// H36M 16-joint adjacency + diag, row bitmasks (bit j set if mask[i][j])
__constant__ unsigned short kMaskBits[16] = {
    0x0093, 0x0007, 0x000E, 0x000C, 0x0031, 0x0070, 0x0060, 0x0181,
    0x4B80, 0x0700, 0x0600, 0x1900, 0x3800, 0x3000, 0xC100, 0xC000};

// 15 att slots: 0=in, 1=cat, 2..9=res[0..7], 10..14=out[0..4]
__global__ void att_kernel(const float* __restrict__ e_in,
                           const float* __restrict__ e_cat,
                           const float* __restrict__ e_res,
                           const float* __restrict__ e_out,
                           float* __restrict__ att_off,
                           float* __restrict__ attd) {
  int t = threadIdx.x;
  if (t >= 240) return;
  int m = t >> 4, i = t & 15;
  const float* e;
  if (m == 0) e = e_in;
  else if (m == 1) e = e_cat;
  else if (m < 10) e = e_res + (m - 2) * 256;
  else e = e_out + (m - 10) * 256;
  unsigned msk = kMaskBits[i];
  float mx = -3.0e38f;
  for (int j = 0; j < 16; ++j)
    if ((msk >> j) & 1) mx = fmaxf(mx, e[i * 16 + j]);
  float v[16];
  float s = 0.0f;
  for (int j = 0; j < 16; ++j) {
    float val = ((msk >> j) & 1) ? expf(e[i * 16 + j] - mx) : 0.0f;
    v[j] = val;
    s += val;
  }
  float inv = 1.0f / s;
  for (int j = 0; j < 16; ++j)
    att_off[m * 256 + i * 16 + j] = (j == i) ? 0.0f : v[j] * inv;
  attd[m * 16 + i] = v[i] * inv;
}

// att -> bf16 B-fragments for mfma_16x16x16: B[k=(l>>4)*4+j][n=l&15].
// slot layout: [2][64][4] bf16 (Bd then Boff), stride 512 shorts.
__global__ void pack_attB(const float* __restrict__ att_off,
                          const float* __restrict__ attd,
                          short* __restrict__ attB) {
  int idx = blockIdx.x * 256 + threadIdx.x;
  if (idx >= 15 * 64) return;
  int slot = idx >> 6, lane = idx & 63;
  int n = lane & 15, q = lane >> 4;
  frag16 bd, bo;
#pragma unroll
  for (int j = 0; j < 4; ++j) {
    int k = q * 4 + j;
    bd[j] = (short)f2bf(k == n ? attd[slot * 16 + n] : 0.0f);
    bo[j] = (short)f2bf(att_off[slot * 256 + n * 16 + k]);  // attoff^T[k][n]
  }
  *(frag16*)(attB + slot * 512 + lane * 4) = bd;
  *(frag16*)(attB + slot * 512 + 256 + lane * 4) = bo;
}

// W_res[8][2][128][128] fp32 -> bf16 B-fragments (16x16x32), unchanged from r2.
__global__ void pack_w_kernel(const float* __restrict__ W_res,
                              short* __restrict__ Wpk) {
  int idx = blockIdx.x * 256 + threadIdx.x;  // 8*64*64 = 32768
  int lane = idx & 63;
  int frag = (idx >> 6) & 63;  // kk*16+nt
  int layer = idx >> 12;
  int kk = frag >> 4, nt = frag & 15;
  int n = nt * 16 + (lane & 15);
  int kbase = kk * 32 + (lane >> 4) * 8;
  int mat = n >> 7, c = n & 127;
  const float* Wsrc = W_res + (((size_t)layer * 2 + mat) * 128) * 128;
  short* dst = Wpk + ((size_t)(layer * 64 + frag)) * 512 + lane * 8;
#pragma unroll
  for (int j = 0; j < 8; ++j)
    dst[j] = (short)f2bf(Wsrc[(size_t)(kbase + j) * 128 + c]);
}

// W_out[5][2][128][3] -> bf16 B-frags, N=16: cols 0-2 = W0, 3-5 = W1, rest 0.
// layout: [5][4 kk][64 lanes][8], layer stride 2048 shorts.
__global__ void pack_wout(const float* __restrict__ W_out,
                          short* __restrict__ Wopk) {
  int idx = blockIdx.x * 256 + threadIdx.x;  // 5*4*64 = 1280
  if (idx >= 1280) return;
  int layer = idx >> 8, rem = idx & 255;
  int kk = rem >> 6, lane = rem & 63;
  int n = lane & 15, q = lane >> 4;
  frag_ab v;
#pragma unroll
  for (int j = 0; j < 8; ++j) {
    int k = kk * 32 + q * 8 + j;
    float val = 0.0f;
    if (n < 3) val = W_out[((size_t)(layer * 2 + 0) * 128 + k) * 3 + n];
    else if (n < 6) val = W_out[((size_t)(layer * 2 + 1) * 128 + k) * 3 + (n - 3)];
    v[j] = (short)f2bf(val);
  }
  *(frag_ab*)(Wopk + ((size_t)(layer * 4 + kk) * 64 + lane) * 8) = v;
}

// ---------------------------------------------------------------------------
// Heavy layer (128x128). Block 256 = 4 waves, 8 batch elems, grid 1024.
// res_mode: bit0 = add residual, bit1 = save residual.
// ---------------------------------------------------------------------------
__launch_bounds__(256, 3)
__global__ void gconv_mfma_kernel(const u16* __restrict__ hin,       // blocked bf16
                                  const float* __restrict__ stats_in,// [32][256]
                                  const float* __restrict__ gamma,
                                  const float* __restrict__ beta,
                                  u16* __restrict__ resbuf,
                                  int res_mode,
                                  const short* __restrict__ Wpk,    // [4][16][64][8]
                                  const float* __restrict__ bias,   // [128]
                                  const short* __restrict__ attB,   // [2][64][4]
                                  u16* __restrict__ hout,           // may == hin
                                  float* __restrict__ stats_out) {  // [32][256]
  __shared__ short Apk[32 * 512];
  __shared__ float sc_s[128], sh_s[128];

  int tid = threadIdx.x;
  int wv = tid >> 6, lane = tid & 63;
  int q = lane >> 4, m = lane & 15;
  int b0 = blockIdx.x * 8;
  int slice = blockIdx.x & (NSLICE - 1);

  frag16 bd = *(const frag16*)(attB + lane * 4);
  frag16 boff = *(const frag16*)(attB + 256 + lane * 4);
  float biasr[2][4];
  *(float4*)biasr[0] = *(const float4*)(bias + wv * 16 + q * 4);
  *(float4*)biasr[1] = *(const float4*)(bias + 64 + wv * 16 + q * 4);

  // ---- phase 0: reduce stats slices -> BN scale/shift in LDS ----
  if (tid < 128) {
    float sum = 0.f, sq = 0.f;
#pragma unroll
    for (int s = 0; s < NSLICE; ++s) {
      sum += stats_in[s * 256 + tid];
      sq += stats_in[s * 256 + 128 + tid];
    }
    const float invN = 1.0f / (float)NROWS;
    float mu = sum * invN;
    float var = fmaxf(sq * invN - mu * mu, 0.f);
    float sc = gamma[tid] * rsqrtf(var + 1e-5f);
    sc_s[tid] = sc;
    sh_s[tid] = beta[tid] - mu * sc;
  }
  __syncthreads();

  // ---- phase 1: A-prep (BN+ReLU+res, bf16) wave wv -> mt {2wv, 2wv+1} ----
#pragma unroll
  for (int mi = 0; mi < 2; ++mi) {
    int mt = wv * 2 + mi;
    size_t bb = (size_t)(b0 + mt) * 2048;
#pragma unroll
    for (int kk = 0; kk < 4; ++kk) {
      size_t base = bb + kk * 512 + q * 128 + m * 8;
      frag_ab hv = *(const frag_ab*)(hin + base);
      const float* scp = &sc_s[kk * 32 + q * 8];
      const float* shp = &sh_s[kk * 32 + q * 8];
      float a[8];
#pragma unroll
      for (int e = 0; e < 8; ++e)
        a[e] = fmaxf(0.f, fmaf(bf2f((unsigned short)hv[e]), scp[e], shp[e]));
      if (res_mode & 1) {
        frag_ab rv = *(const frag_ab*)(resbuf + base);
#pragma unroll
        for (int e = 0; e < 8; ++e) a[e] += bf2f((unsigned short)rv[e]);
      }
      frag_ab av;
#pragma unroll
      for (int e = 0; e < 8; ++e) av[e] = (short)f2bf(a[e]);
      *(frag_ab*)&Apk[(mt * 4 + kk) * 512 + lane * 8] = av;
      if (res_mode & 2) *(frag_ab*)(resbuf + base) = av;
    }
  }
  __syncthreads();

  // ---- phase 2: GEMM + MFMA mix epilogue ----
  float ssum[2][4] = {{0.f}}, ssq[2][4] = {{0.f}};
  for (int half = 0; half < 2; ++half) {
    frag_cd acc[4][4];
#pragma unroll
    for (int mi = 0; mi < 4; ++mi)
#pragma unroll
      for (int t = 0; t < 4; ++t) acc[mi][t] = (frag_cd){0.f, 0.f, 0.f, 0.f};

#pragma unroll
    for (int kk = 0; kk < 4; ++kk) {
      frag_ab bfr[4];
#pragma unroll
      for (int t = 0; t < 4; ++t) {
        int nt = wv + 4 * t;
        bfr[t] = *(const frag_ab*)(Wpk + ((kk * 16 + nt) * 64 + lane) * 8);
      }
#pragma unroll
      for (int mi = 0; mi < 4; ++mi) {
        frag_ab af = *(const frag_ab*)&Apk[((half * 4 + mi) * 4 + kk) * 512 + lane * 8];
#pragma unroll
        for (int t = 0; t < 4; ++t)
          acc[mi][t] = __builtin_amdgcn_mfma_f32_16x16x32_bf16(af, bfr[t],
                                                               acc[mi][t], 0, 0, 0);
      }
    }

    // epilogue: Out^T = Y0^T*Bd + Y1^T*Boff + bias; store blocked bf16
#pragma unroll
    for (int mi = 0; mi < 4; ++mi) {
      size_t bb = (size_t)(b0 + half * 4 + mi) * 2048;
#pragma unroll
      for (int p = 0; p < 2; ++p) {
        frag16 a0, a1;
#pragma unroll
        for (int r = 0; r < 4; ++r) {
          a0[r] = (short)f2bf(acc[mi][p][r]);
          a1[r] = (short)f2bf(acc[mi][p + 2][r]);
        }
        frag_cd d = (frag_cd){0.f, 0.f, 0.f, 0.f};
        d = __builtin_amdgcn_mfma_f32_16x16x16bf16_1k(a0, bd, d, 0, 0, 0);
        d = __builtin_amdgcn_mfma_f32_16x16x16bf16_1k(a1, boff, d, 0, 0, 0);
        int colbase = (p == 0) ? wv * 16 : 64 + wv * 16;
        frag16 sv;
#pragma unroll
        for (int r = 0; r < 4; ++r) {
          float v = d[r] + biasr[p][r];
          ssum[p][r] += v;
          ssq[p][r] = fmaf(v, v, ssq[p][r]);
          sv[r] = (short)f2bf(v);
        }
        size_t addr = bb + (size_t)(colbase / 8 + (q >> 1)) * 128 + m * 8 + (q & 1) * 4;
        *(frag16*)(hout + addr) = sv;
      }
    }
  }

  // ---- phase 3: BN stats (cross-i shuffle reduce, sliced atomics) ----
#pragma unroll
  for (int p = 0; p < 2; ++p)
#pragma unroll
    for (int r = 0; r < 4; ++r) {
      float v1 = ssum[p][r], v2 = ssq[p][r];
      v1 += __shfl_xor(v1, 1); v2 += __shfl_xor(v2, 1);
      v1 += __shfl_xor(v1, 2); v2 += __shfl_xor(v2, 2);
      v1 += __shfl_xor(v1, 4); v2 += __shfl_xor(v2, 4);
      v1 += __shfl_xor(v1, 8); v2 += __shfl_xor(v2, 8);
      if (m == 0) {
        int c = ((p == 0) ? wv * 16 : 64 + wv * 16) + q * 4 + r;
        atomicAdd(&stats_out[slice * 256 + c], v1);
        atomicAdd(&stats_out[slice * 256 + 128 + c], v2);
      }
    }
}

// ---------------------------------------------------------------------------
// Small-K layers (Fin=2, Fin=12): fp32 VALU, blocked bf16 output via LDS.
// Block 256 = 128 ch x 2 b. Grid 4096.
// ---------------------------------------------------------------------------
template <int FIN>
__launch_bounds__(256)
__global__ void gconv_kernel(const float* __restrict__ hin,   // [B,16,FIN] fp32
                             const float* __restrict__ W,     // [2][FIN][128]
                             const float* __restrict__ bias,  // [128]
                             const float* __restrict__ attoff,
                             const float* __restrict__ attd_p,
                             u16* __restrict__ hout,          // blocked bf16
                             float* __restrict__ stats_out) { // [32][256]
  __shared__ float xin[2][NJ][FIN];
  __shared__ float att_s[256];
  __shared__ float attd_s[16];
  __shared__ float red[256];
  __shared__ short xout[2][NJ][128];

  int tid = threadIdx.x;
  int b0 = blockIdx.x * 2;
  int slice = blockIdx.x & (NSLICE - 1);

  att_s[tid] = attoff[tid];
  if (tid < 16) attd_s[tid] = attd_p[tid];

  const int TOT4 = 2 * NJ * FIN / 4;
  const float4* hin4 = (const float4*)(hin + (size_t)b0 * NJ * FIN);
  for (int k = tid; k < TOT4; k += 256)
    ((float4*)&xin[0][0][0])[k] = hin4[k];
  __syncthreads();

  int o = tid & 127;
  int bl = tid >> 7;
  float acc0[16], acc1[16];
#pragma unroll
  for (int j = 0; j < 16; ++j) { acc0[j] = 0.0f; acc1[j] = 0.0f; }
  const float* W0 = W;
  const float* W1 = W + FIN * FHID;
  if constexpr (FIN % 4 == 0) {
    for (int f = 0; f < FIN; f += 4) {
      float w00 = W0[(f + 0) * FHID + o], w01 = W0[(f + 1) * FHID + o];
      float w02 = W0[(f + 2) * FHID + o], w03 = W0[(f + 3) * FHID + o];
      float w10 = W1[(f + 0) * FHID + o], w11 = W1[(f + 1) * FHID + o];
      float w12 = W1[(f + 2) * FHID + o], w13 = W1[(f + 3) * FHID + o];
#pragma unroll
      for (int j = 0; j < 16; ++j) {
        float4 xv = *(const float4*)&xin[bl][j][f];
        acc0[j] = fmaf(xv.x, w00, fmaf(xv.y, w01, fmaf(xv.z, w02, fmaf(xv.w, w03, acc0[j]))));
        acc1[j] = fmaf(xv.x, w10, fmaf(xv.y, w11, fmaf(xv.z, w12, fmaf(xv.w, w13, acc1[j]))));
      }
    }
  } else {
    for (int f = 0; f < FIN; ++f) {
      float w0 = W0[f * FHID + o], w1 = W1[f * FHID + o];
#pragma unroll
      for (int j = 0; j < 16; ++j) {
        float xv = xin[bl][j][f];
        acc0[j] = fmaf(xv, w0, acc0[j]);
        acc1[j] = fmaf(xv, w1, acc1[j]);
      }
    }
  }

  float bo = bias[o];
  float ssum = 0.0f, ssq = 0.0f;
#pragma unroll
  for (int i = 0; i < 16; ++i) {
    float h = fmaf(attd_s[i], acc0[i], bo);
#pragma unroll
    for (int j = 0; j < 16; ++j) h = fmaf(att_s[i * 16 + j], acc1[j], h);
    xout[bl][i][o] = (short)f2bf(h);
    ssum += h;
    ssq = fmaf(h, h, ssq);
  }
  __syncthreads();
  red[tid] = ssum;
  __syncthreads();
  if (bl == 0) atomicAdd(&stats_out[slice * 256 + o], ssum + red[o + 128]);
  __syncthreads();
  red[tid] = ssq;
  __syncthreads();
  if (bl == 0) atomicAdd(&stats_out[slice * 256 + 128 + o], ssq + red[o + 128]);
  __syncthreads();

  // blocked bf16 write: chunk q = (b_l, g, i) -> 16B coalesced stores
  for (int qq = tid; qq < 512; qq += 256) {
    int b_l = qq >> 8, g = (qq >> 4) & 15, ii = qq & 15;
    *(frag_ab*)(hout + (size_t)(b0 + b_l) * 2048 + g * 128 + ii * 8) =
        *(const frag_ab*)&xout[b_l][ii][g * 8];
  }
}

// ---------------------------------------------------------------------------
// Output gconv (Fout=3) via MFMA, N=16 (3 W0-cols + 3 W1-cols). Grid 1024.
// Always BN + residual-add. Mix via wave-private LDS (tiny).
// ---------------------------------------------------------------------------
__launch_bounds__(256, 4)
__global__ void gconv_out_kernel(const u16* __restrict__ hin,
                                 const float* __restrict__ stats_in,
                                 const float* __restrict__ gamma,
                                 const float* __restrict__ beta,
                                 const u16* __restrict__ resbuf,
                                 const short* __restrict__ Wopk,  // [4][64][8]
                                 const float* __restrict__ bias,  // [3]
                                 const float* __restrict__ attoff,
                                 const float* __restrict__ attd_p,
                                 float* __restrict__ out) {       // [B,16,3]
  __shared__ float sc_s[128], sh_s[128];
  __shared__ float att_s[256];
  __shared__ float attd_s[16];
  __shared__ float ys[4][6][16];

  int tid = threadIdx.x;
  int wv = tid >> 6, lane = tid & 63;
  int q = lane >> 4, m = lane & 15;
  int b0 = blockIdx.x * 8;

  att_s[tid] = attoff[tid];
  if (tid < 16) attd_s[tid] = attd_p[tid];
  if (tid < 128) {
    float sum = 0.f, sq = 0.f;
#pragma unroll
    for (int s = 0; s < NSLICE; ++s) {
      sum += stats_in[s * 256 + tid];
      sq += stats_in[s * 256 + 128 + tid];
    }
    const float invN = 1.0f / (float)NROWS;
    float mu = sum * invN;
    float var = fmaxf(sq * invN - mu * mu, 0.f);
    float sc = gamma[tid] * rsqrtf(var + 1e-5f);
    sc_s[tid] = sc;
    sh_s[tid] = beta[tid] - mu * sc;
  }
  __syncthreads();

  frag_ab bfr[4];
#pragma unroll
  for (int kk = 0; kk < 4; ++kk)
    bfr[kk] = *(const frag_ab*)(Wopk + (kk * 64 + lane) * 8);

  for (int mi = 0; mi < 2; ++mi) {
    int b = b0 + wv * 2 + mi;
    size_t bb = (size_t)b * 2048;
    frag_cd acc = (frag_cd){0.f, 0.f, 0.f, 0.f};
#pragma unroll
    for (int kk = 0; kk < 4; ++kk) {
      size_t base = bb + kk * 512 + q * 128 + m * 8;
      frag_ab hv = *(const frag_ab*)(hin + base);
      frag_ab rv = *(const frag_ab*)(resbuf + base);
      const float* scp = &sc_s[kk * 32 + q * 8];
      const float* shp = &sh_s[kk * 32 + q * 8];
      frag_ab av;
#pragma unroll
      for (int e = 0; e < 8; ++e) {
        float a = fmaxf(0.f, fmaf(bf2f((unsigned short)hv[e]), scp[e], shp[e])) +
                  bf2f((unsigned short)rv[e]);
        av[e] = (short)f2bf(a);
      }
      acc = __builtin_amdgcn_mfma_f32_16x16x32_bf16(av, bfr[kk], acc, 0, 0, 0);
    }
    // acc: lane holds Y[i=q*4+r][n=m] (n<3: Y0 col n; 3<=n<6: Y1 col n-3)
    if (m < 6) {
#pragma unroll
      for (int r = 0; r < 4; ++r) ys[wv][m][q * 4 + r] = acc[r];
    }
    // same-wave LDS ops are in-order; no barrier needed
    if (q < 3) {
      float v = bias[q] + attd_s[m] * ys[wv][q][m];
#pragma unroll
      for (int j = 0; j < 16; ++j) v = fmaf(att_s[m * 16 + j], ys[wv][3 + q][j], v);
      out[((size_t)b * 16 + m) * 3 + q] = v;
    }
  }
}

// merged[b,j,c] = out_{1+c/3}[b,j,c%3]; out_i at d_out + i*393216
__global__ void pack_merged(const float* __restrict__ dout, float* __restrict__ merged) {
  int idx = blockIdx.x * 256 + threadIdx.x;
  if (idx >= BATCH * NJ * 12) return;
  int c = idx % 12;
  int bj = idx / 12;
  merged[idx] = dout[(size_t)(1 + c / 3) * 393216 + (size_t)bj * 3 + (c % 3)];
}

extern "C" void kernel_launch(void* const* d_in, const int* in_sizes, int n_in,
                              void* d_out, int out_size, void* d_ws, size_t ws_size,
                              hipStream_t stream) {
  (void)in_sizes; (void)n_in; (void)out_size; (void)ws_size;
  const float* W_in = (const float*)d_in[4];
  const float* b_in = (const float*)d_in[5];
  const float* e_in = (const float*)d_in[6];
  const float* g_in = (const float*)d_in[7];
  const float* beta_in = (const float*)d_in[8];
  const float* W_cat = (const float*)d_in[9];
  const float* b_cat = (const float*)d_in[10];
  const float* e_cat = (const float*)d_in[11];
  const float* g_cat = (const float*)d_in[12];
  const float* beta_cat = (const float*)d_in[13];
  const float* W_res = (const float*)d_in[14];
  const float* b_res = (const float*)d_in[15];
  const float* e_res = (const float*)d_in[16];
  const float* g_res = (const float*)d_in[17];
  const float* beta_res = (const float*)d_in[18];
  const float* W_out = (const float*)d_in[19];
  const float* b_out = (const float*)d_in[20];
  const float* e_out = (const float*)d_in[21];

  float* ws = (float*)d_ws;
  float* att_off = ws;                          // 3840 fl
  float* attd = att_off + 3840;                 // 240 fl (pad to 256)
  short* attB = (short*)(attd + 256);           // 15*512 shorts
  short* Wpk = attB + 15 * 512;                 // 8*64*512 = 262144 shorts
  short* Wopk = Wpk + 262144;                   // 5*2048 = 10240 shorts
  float* stats = (float*)(Wopk + 10240);        // 45 slots x 32 x 256 fl
  float* merged = stats + 45 * NSLICE * 256;    // B*16*12 fl
  u16* hbuf = (u16*)(merged + (size_t)BATCH * NJ * 12);  // 16777216 u16
  u16* R = hbuf + (size_t)BATCH * NJ * FHID;             // 16777216 u16

  hipMemsetAsync(stats, 0, 45 * NSLICE * 256 * sizeof(float), stream);
  att_kernel<<<1, 256, 0, stream>>>(e_in, e_cat, e_res, e_out, att_off, attd);
  pack_attB<<<4, 256, 0, stream>>>(att_off, attd, attB);
  pack_w_kernel<<<128, 256, 0, stream>>>(W_res, Wpk);
  pack_wout<<<5, 256, 0, stream>>>(W_out, Wopk);

  float* dout = (float*)d_out;
  const int SSTRIDE = NSLICE * 256;

  auto run_stack = [&](int sb, const float* g0, const float* bt0, int out_layer,
                       const float* bo, int att_out_slot, float* optr) {
    for (int k = 0; k < 8; ++k) {
      const float* gg = (k == 0) ? g0 : g_res + (size_t)(k - 1) * FHID;
      const float* bb = (k == 0) ? bt0 : beta_res + (size_t)(k - 1) * FHID;
      int rm = (k == 0) ? 2 : ((k % 2 == 0) ? 3 : 0);
      gconv_mfma_kernel<<<BATCH / 8, 256, 0, stream>>>(
          hbuf, stats + (size_t)(sb + k) * SSTRIDE, gg, bb, R, rm,
          Wpk + (size_t)k * 32768, b_res + (size_t)k * FHID,
          attB + (size_t)(2 + k) * 512, hbuf,
          stats + (size_t)(sb + k + 1) * SSTRIDE);
    }
    gconv_out_kernel<<<BATCH / 8, 256, 0, stream>>>(
        hbuf, stats + (size_t)(sb + 8) * SSTRIDE, g_res + 7 * FHID,
        beta_res + 7 * FHID, R, Wopk + (size_t)out_layer * 2048, bo,
        att_off + (size_t)att_out_slot * 256, attd + (size_t)att_out_slot * 16,
        optr);
  };

  for (int bi = 0; bi < 4; ++bi) {
    gconv_kernel<2><<<BATCH / 2, 256, 0, stream>>>(
        (const float*)d_in[bi], W_in, b_in, att_off, attd, hbuf,
        stats + (size_t)(bi * 9) * SSTRIDE);
    run_stack(bi * 9, g_in, beta_in, bi, b_out + bi * 3, 10 + bi,
              dout + (size_t)(1 + bi) * 393216);
  }

  pack_merged<<<(BATCH * NJ * 12 + 255) / 256, 256, 0, stream>>>(dout, merged);
  gconv_kernel<12><<<BATCH / 2, 256, 0, stream>>>(
      merged, W_cat, b_cat, att_off + 256, attd + 16, hbuf,
      stats + (size_t)36 * SSTRIDE);
  run_stack(36, g_cat, beta_cat, 4, b_out + 12, 14, dout);
}